// Round 4
// baseline (148.812 us; speedup 1.0000x reference)
//
#include <hip/hip_runtime.h>
#include <hip/hip_bf16.h>

// EdgePredictor: out[e] = relu(concat(X[row], X[col]) @ W1 + b1) @ W2 + b2
// Precompute per-node AB[n][256] = {X[n]@W1[:128,:] | X[n]@W1[128:,:]} in f16.
// Per edge: out = relu(A[row] + B[col] + b1) @ W2 + b2.
//
// R13: R12's VGPR=64 proved the 2-deep pipeline STILL didn't materialize:
// sched_barrier(0) binds only within a scheduling region; the gathers sat
// in `if (h)` blocks and MachineSink (cross-BB, ignores sched_barrier)
// sank them to their uses. Fix: make the steady-state loop body ONE basic
// block — no pipeline guards (dummy clamped groups run unconditionally),
// branchless mode select (index shift), branchless stores (address select
// to a per-lane dump slot for non-real lanes). With a single BB, sinking
// is impossible and the SB pins hold: both gather sets stay live
// (expect VGPR ~130-150). Decisive test of the concurrency hypothesis;
// LLC-resident reps at 40.8us (FETCH 4MB) show the limiter is latency
// serialization, invariant to hit tier.

#define EMBED 128

typedef _Float16 half8 __attribute__((ext_vector_type(8)));
typedef _Float16 half4 __attribute__((ext_vector_type(4)));
typedef float floatx4 __attribute__((ext_vector_type(4)));

// --- Kernel 0: fused prep.
// Blocks 0..127: transpose+convert W1 (256x128 f32) -> WT (256x128 f16),
//   WT[j][k] = Wcat[k][j] (Wcat = [W1 top | W1 bottom] per concat split).
// Block 128: idx-mode ballot detect; W2PT[16][128] f16; b1f[128] f16.
__global__ __launch_bounds__(256) void prep(
    const float* __restrict__ W1, const float* __restrict__ W2,
    const float* __restrict__ b1, const int* __restrict__ idx,
    _Float16* __restrict__ WT, _Float16* __restrict__ W2PT,
    _Float16* __restrict__ b1f, int* __restrict__ flag) {
    if (blockIdx.x < 128) {
        __shared__ float lds[16][17];
        const int ty = threadIdx.x >> 4, tx = threadIdx.x & 15;
        const int r0 = (blockIdx.x >> 3) * 16;   // source W1 row tile
        const int c0 = (blockIdx.x & 7) * 16;    // source W1 col tile
        lds[ty][tx] = W1[(r0 + ty) * 128 + c0 + tx];
        __syncthreads();
        const int jbase = c0 + (r0 >= 128 ? 128 : 0);
        const int kbase = r0 & 127;
        WT[(size_t)(jbase + ty) * 128 + kbase + tx] = (_Float16)lds[tx][ty];
    } else {
        const int t = threadIdx.x;
        if (t < 64) {  // int64 layout iff first 64 high words are all zero
            const int hw = idx[2 * t + 1];
            const unsigned long long m = __ballot(hw != 0);
            if (t == 0) *flag = (m == 0ull) ? 1 : 0;
        }
        if (t < 128) b1f[t] = (_Float16)b1[t];
        for (int i = t; i < 2048; i += 256) {  // W2PT[n][k] = n<2 ? W2[k][n] : 0
            const int n = i >> 7, k = i & 127;
            W2PT[i] = (n < 2) ? (_Float16)W2[k * 2 + n] : (_Float16)0.f;
        }
    }
}

// --- Kernel 1: AB = [X | X] @ Wcat via f16 MFMA, operand-swapped
// (A-operand = W-frag so D rows are output cols). Grid-stride, 2 tiles per
// block; next tile's X loads prefetched into registers during compute.
__global__ __launch_bounds__(256) void gemm_ab(
    const float* __restrict__ X, const _Float16* __restrict__ WT,
    _Float16* __restrict__ AB, int n_nodes, int n_tiles) {
    __shared__ _Float16 sh[64 * 264];  // 33792 B union: xs(17408) / outs(33792)
    _Float16* xs   = sh;               // stride 136
    _Float16* outs = sh;               // stride 264
    const int t = threadIdx.x;
    const int w = t >> 6, lane = t & 63, lm = lane & 15, quad = lane >> 4;

    // Per-thread stage coordinates (fixed across tiles).
    int srow[8], scol[8];
#pragma unroll
    for (int i = 0; i < 8; ++i) {
        const int flat = i * 1024 + t * 4;
        srow[i] = flat >> 7;
        scol[i] = flat & 127;
    }

    int T = blockIdx.x;
    float4 pf[8];
    if (T < n_tiles) {  // prefetch first tile
#pragma unroll
        for (int i = 0; i < 8; ++i) {
            int node = T * 64 + srow[i];
            if (node > n_nodes - 1) node = n_nodes - 1;  // clamp; never stored
            pf[i] = *(const float4*)(X + (size_t)node * EMBED + scol[i]);
        }
    }

    for (; T < n_tiles; T += gridDim.x) {
        const int mblk = T * 64;

        // Stage: spill prefetched registers to LDS (convert f32->f16 once).
#pragma unroll
        for (int i = 0; i < 8; ++i) {
            half4 h;
            h[0] = (_Float16)pf[i].x; h[1] = (_Float16)pf[i].y;
            h[2] = (_Float16)pf[i].z; h[3] = (_Float16)pf[i].w;
            *(half4*)(xs + srow[i] * 136 + scol[i]) = h;
        }
        __syncthreads();  // S1: stage visible

        // Prefetch next tile NOW — loads overlap this tile's MFMA+epilogue.
        const int Tn = T + gridDim.x;
        if (Tn < n_tiles) {
#pragma unroll
            for (int i = 0; i < 8; ++i) {
                int node = Tn * 64 + srow[i];
                if (node > n_nodes - 1) node = n_nodes - 1;
                pf[i] = *(const float4*)(X + (size_t)node * EMBED + scol[i]);
            }
        }

        floatx4 acc[4][4];  // [mf: node tile][jf: col tile]
#pragma unroll
        for (int a = 0; a < 4; ++a)
#pragma unroll
            for (int b = 0; b < 4; ++b)
                acc[a][b] = (floatx4){0.f, 0.f, 0.f, 0.f};

#pragma unroll
        for (int ks = 0; ks < 4; ++ks) {
            const int k0 = ks * 32 + quad * 8;
            half8 xf[4];  // B-operand: B[k][n=lane&15] = Xf16[node mf*16+lm][k]
#pragma unroll
            for (int mf = 0; mf < 4; ++mf)
                xf[mf] = *(const half8*)(xs + (mf * 16 + lm) * 136 + k0);
#pragma unroll
            for (int jf = 0; jf < 4; ++jf) {
                const int j = w * 64 + jf * 16 + lm;  // A-op: WT row = out col
                const half8 wf = *(const half8*)(WT + (size_t)j * EMBED + k0);
#pragma unroll
                for (int mf = 0; mf < 4; ++mf)
                    acc[mf][jf] = __builtin_amdgcn_mfma_f32_16x16x32_f16(wf, xf[mf], acc[mf][jf], 0, 0, 0);
            }
        }
        __syncthreads();  // S2: xs reads done before outs overwrites union

        // Pack D into LDS out tile: node-major [local node][j], stride 264.
        // D: col(lane&15) = node within mf-tile, row(quad*4+r) = output col j.
#pragma unroll
        for (int mf = 0; mf < 4; ++mf) {
#pragma unroll
            for (int jf = 0; jf < 4; ++jf) {
                half4 h;
#pragma unroll
                for (int r = 0; r < 4; ++r) h[r] = (_Float16)acc[mf][jf][r];
                *(half4*)(outs + (mf * 16 + lm) * 264 + w * 64 + jf * 16 + quad * 4) = h;
            }
        }
        __syncthreads();  // S3: outs visible

        // Coalesced store: 64 nodes x 512 B contiguous in AB (node-major).
#pragma unroll
        for (int i = 0; i < 8; ++i) {
            const int idx8 = i * 256 + t;         // half8 index in 64x256 tile
            const int node = idx8 >> 5, jj = idx8 & 31;
            if (mblk + node < n_nodes)
                *(half8*)(AB + (size_t)(mblk + node) * 256 + jj * 8) =
                    *(const half8*)(outs + node * 264 + jj * 8);
        }
        __syncthreads();  // S4: outs reads done before next tile's stage
    }
}

// --- Kernel 2: per-edge MLP. 16 edges per wave-group, persistent waves,
// 2-deep software pipeline. R13: the ENTIRE steady-state body is one
// basic block — no `if` anywhere inside the loop (dummy clamped groups
// run unconditionally; stores use branchless address selects into a
// per-lane dump slot; mode select is an index shift). MachineSink cannot
// fire (no CFG), so sched_barrier(0) pins hold: while comp(g) reads set
// A, set B's 8 gathers + next indices are genuinely outstanding.
__global__ __launch_bounds__(256, 3) void edge_mlp(
    const _Float16* __restrict__ AB, const int* __restrict__ eidx,
    const int* __restrict__ flag, const _Float16* __restrict__ b1f,
    const _Float16* __restrict__ W2PT, const float* __restrict__ b2,
    float* __restrict__ out, float* __restrict__ dump, int n_edges) {
    const int lane = threadIdx.x & 63, lm = lane & 15, quad = lane >> 4;
    const int W = gridDim.x * 4;               // total waves
    const int G = (n_edges + 15) / 16;         // 16-edge groups
    const int wid = blockIdx.x * 4 + (threadIdx.x >> 6);
    if (wid >= G) return;

    const int mode = *flag;        // wave-uniform: 1 => int64-layout indices
    const float b2v = b2[lm & 1];  // only meaningful when lm<2
    float* const dslot = dump + (size_t)wid * 64 + lane;  // per-lane sink

    // Loop-invariant operands in registers (completed before the loop).
    half8 wv[4], bv[4];
#pragma unroll
    for (int ks = 0; ks < 4; ++ks) {
        wv[ks] = *(const half8*)(W2PT + lm * 128 + ks * 32 + quad * 8);
        bv[ks] = *(const half8*)(b1f + ks * 32 + quad * 8);
    }

    // Branchless index load: lane lm serves edge g*16+lm (clamped).
    auto ldidx = [&](int g, int& r, int& c) {
        int e = g * 16 + lm;
        e = e < n_edges ? e : n_edges - 1;
        r = eidx[(size_t)e << mode];
        c = eidx[((size_t)n_edges + e) << mode];
    };

    // Issue the 8 gathers for one group (each b128: 16 edges x one 64B line).
    auto gather = [&](int r, int c, half8* d) {
        const _Float16* ap = AB + (size_t)r * 256;
        const _Float16* bp = AB + (size_t)c * 256 + 128;
#pragma unroll
        for (int ks = 0; ks < 4; ++ks) {
            const int k0 = ks * 32 + quad * 8;
            d[ks]     = *(const half8*)(ap + k0);
            d[ks + 4] = *(const half8*)(bp + k0);
        }
    };

    // Branchless compute+store: every lane stores 4 floats; non-real lanes
    // (lm>=2 or tail) hit their private dump slot.
    auto comp = [&](int g, const half8* d) {
        floatx4 acc = (floatx4){0.f, 0.f, 0.f, 0.f};
#pragma unroll
        for (int ks = 0; ks < 4; ++ks) {
            half8 h = d[ks] + d[ks + 4] + bv[ks];
#pragma unroll
            for (int j = 0; j < 8; ++j)
                h[j] = h[j] > (_Float16)0.f ? h[j] : (_Float16)0.f;
            acc = __builtin_amdgcn_mfma_f32_16x16x32_f16(h, wv[ks], acc, 0, 0, 0);
        }
        const int eb = g * 16;
#pragma unroll
        for (int r = 0; r < 4; ++r) {
            const int ed = eb + quad * 4 + r;
            const bool real = (lm < 2) & (ed < n_edges);
            float* sp = real ? out + (size_t)ed * 2 + lm : dslot;
            *sp = acc[r] + b2v;
        }
    };

    // ---- pipeline prologue (outside the loop; its own BBs are fine) ----
    int g0 = wid, g1 = wid + W;
    int r0, c0, r1, c1;
    ldidx(g0, r0, c0);
    ldidx(g1, r1, c1);
    half8 a0[8], a1[8];
    gather(r0, c0, a0);
    __builtin_amdgcn_sched_barrier(0);

    // ---- steady state: 2 phases/iter, zero branches in the body ----
    const int n = (G - wid + W - 1) / W;   // real groups for this wave (>=1)
    const int nloop = (n + 1) >> 1;        // odd n => one harmless dummy phase
    for (int it = 0; it < nloop; ++it) {
        // Phase A: comp(g0,a0); gather(g1)->a1; idx(g0+2W)->r0,c0.
        const int g2 = g1 + W;
        ldidx(g2, r0, c0);
        __builtin_amdgcn_sched_barrier(0);
        gather(r1, c1, a1);
        __builtin_amdgcn_sched_barrier(0);
        comp(g0, a0);
        __builtin_amdgcn_sched_barrier(0);
        // Phase B: comp(g1,a1); gather(g2)->a0; idx(g1+2W)->r1,c1.
        const int g3 = g2 + W;
        ldidx(g3, r1, c1);
        __builtin_amdgcn_sched_barrier(0);
        gather(r0, c0, a0);
        __builtin_amdgcn_sched_barrier(0);
        comp(g1, a1);
        __builtin_amdgcn_sched_barrier(0);
        g0 += 2 * W;
        g1 += 2 * W;
    }
}

extern "C" void kernel_launch(void* const* d_in, const int* in_sizes, int n_in,
                              void* d_out, int out_size, void* d_ws, size_t ws_size,
                              hipStream_t stream) {
    const float* X   = (const float*)d_in[0];
    const int*   idx = (const int*)d_in[1];
    const float* W1  = (const float*)d_in[2];
    const float* b1  = (const float*)d_in[3];
    const float* W2  = (const float*)d_in[4];
    const float* b2  = (const float*)d_in[5];
    float* out = (float*)d_out;

    const int n_nodes = in_sizes[0] / EMBED;   // 100000
    const int n_edges = in_sizes[1] / 2;       // 500000

    // ws: flag @0 | AB @256 (n_nodes*512 B) | WT 64KB | W2PT 4KB | b1f 256B
    //     | dump 3072 waves x 256B
    char* ws = (char*)d_ws;
    int*      flag = (int*)ws;
    _Float16* AB   = (_Float16*)(ws + 256);
    _Float16* WT   = (_Float16*)(ws + 256 + (size_t)n_nodes * 512);
    _Float16* W2PT = WT + 256 * 128;
    _Float16* b1f  = W2PT + 16 * 128;
    float*    dump = (float*)(b1f + 128);

    const int n_tiles = (n_nodes + 63) / 64;   // 1563

    prep<<<129, 256, 0, stream>>>(W1, W2, b1, idx, WT, W2PT, b1f, flag);
    gemm_ab<<<782, 256, 0, stream>>>(X, WT, AB, n_nodes, n_tiles);
    // 768 persistent blocks = 3 blocks/CU x 4 waves = 12 waves/CU at the
    // (256,3) VGPR cap; ~10 groups/wave keeps the 2-deep pipeline filled.
    edge_mlp<<<768, 256, 0, stream>>>(
        AB, idx, flag, b1f, W2PT, b2, out, dump, n_edges);
}

// Round 5
// 144.893 us; speedup vs baseline: 1.0270x; 1.0270x over previous
//
#include <hip/hip_runtime.h>
#include <hip/hip_bf16.h>

// EdgePredictor: out[e] = relu(concat(X[row], X[col]) @ W1 + b1) @ W2 + b2
// Precompute per-node AB[n][256] = {X[n]@W1[:128,:] | X[n]@W1[128:,:]} in f16.
// Per edge: out = relu(A[row] + B[col] + b1) @ W2 + b2.
//
// R14: three rounds of source-level pipelining all died at VGPR=60-64 (the
// compiler refuses to keep two gather sets live; waitcnt insertion drains
// per group). This round the edge_mlp loop's memory ops are ALL inline asm
// with hand-counted s_waitcnt vmcnt(N): the "=v" outputs of one phase's
// gathers are consumed a phase later, so the RA MUST keep both sets live,
// and the only waits are vmcnt(12)/vmcnt(14) — never a drain. Steady-state
// queue: [S(4) I(2) G(8) S(4)]=18 -> wait12 (idx ready) -> +I(2)+G(8)=22
// -> wait14 (set ready) -> comp+4 stores. Prologue pads 4 dummy stores to
// enter the loop in steady shape. Decisive test: VGPR>=120 or bust.

#define EMBED 128

typedef _Float16 half8 __attribute__((ext_vector_type(8)));
typedef _Float16 half4 __attribute__((ext_vector_type(4)));
typedef float floatx4 __attribute__((ext_vector_type(4)));

// --- Kernel 0: fused prep.
// Blocks 0..127: transpose+convert W1 (256x128 f32) -> WT (256x128 f16),
//   WT[j][k] = Wcat[k][j] (Wcat = [W1 top | W1 bottom] per concat split).
// Block 128: idx-mode ballot detect; W2PT[16][128] f16; b1f[128] f16.
__global__ __launch_bounds__(256) void prep(
    const float* __restrict__ W1, const float* __restrict__ W2,
    const float* __restrict__ b1, const int* __restrict__ idx,
    _Float16* __restrict__ WT, _Float16* __restrict__ W2PT,
    _Float16* __restrict__ b1f, int* __restrict__ flag) {
    if (blockIdx.x < 128) {
        __shared__ float lds[16][17];
        const int ty = threadIdx.x >> 4, tx = threadIdx.x & 15;
        const int r0 = (blockIdx.x >> 3) * 16;   // source W1 row tile
        const int c0 = (blockIdx.x & 7) * 16;    // source W1 col tile
        lds[ty][tx] = W1[(r0 + ty) * 128 + c0 + tx];
        __syncthreads();
        const int jbase = c0 + (r0 >= 128 ? 128 : 0);
        const int kbase = r0 & 127;
        WT[(size_t)(jbase + ty) * 128 + kbase + tx] = (_Float16)lds[tx][ty];
    } else {
        const int t = threadIdx.x;
        if (t < 64) {  // int64 layout iff first 64 high words are all zero
            const int hw = idx[2 * t + 1];
            const unsigned long long m = __ballot(hw != 0);
            if (t == 0) *flag = (m == 0ull) ? 1 : 0;
        }
        if (t < 128) b1f[t] = (_Float16)b1[t];
        for (int i = t; i < 2048; i += 256) {  // W2PT[n][k] = n<2 ? W2[k][n] : 0
            const int n = i >> 7, k = i & 127;
            W2PT[i] = (n < 2) ? (_Float16)W2[k * 2 + n] : (_Float16)0.f;
        }
    }
}

// --- Kernel 1: AB = [X | X] @ Wcat via f16 MFMA, operand-swapped
// (A-operand = W-frag so D rows are output cols). Grid-stride, 2 tiles per
// block; next tile's X loads prefetched into registers during compute.
__global__ __launch_bounds__(256) void gemm_ab(
    const float* __restrict__ X, const _Float16* __restrict__ WT,
    _Float16* __restrict__ AB, int n_nodes, int n_tiles) {
    __shared__ _Float16 sh[64 * 264];  // 33792 B union: xs(17408) / outs(33792)
    _Float16* xs   = sh;               // stride 136
    _Float16* outs = sh;               // stride 264
    const int t = threadIdx.x;
    const int w = t >> 6, lane = t & 63, lm = lane & 15, quad = lane >> 4;

    // Per-thread stage coordinates (fixed across tiles).
    int srow[8], scol[8];
#pragma unroll
    for (int i = 0; i < 8; ++i) {
        const int flat = i * 1024 + t * 4;
        srow[i] = flat >> 7;
        scol[i] = flat & 127;
    }

    int T = blockIdx.x;
    float4 pf[8];
    if (T < n_tiles) {  // prefetch first tile
#pragma unroll
        for (int i = 0; i < 8; ++i) {
            int node = T * 64 + srow[i];
            if (node > n_nodes - 1) node = n_nodes - 1;  // clamp; never stored
            pf[i] = *(const float4*)(X + (size_t)node * EMBED + scol[i]);
        }
    }

    for (; T < n_tiles; T += gridDim.x) {
        const int mblk = T * 64;

        // Stage: spill prefetched registers to LDS (convert f32->f16 once).
#pragma unroll
        for (int i = 0; i < 8; ++i) {
            half4 h;
            h[0] = (_Float16)pf[i].x; h[1] = (_Float16)pf[i].y;
            h[2] = (_Float16)pf[i].z; h[3] = (_Float16)pf[i].w;
            *(half4*)(xs + srow[i] * 136 + scol[i]) = h;
        }
        __syncthreads();  // S1: stage visible

        // Prefetch next tile NOW — loads overlap this tile's MFMA+epilogue.
        const int Tn = T + gridDim.x;
        if (Tn < n_tiles) {
#pragma unroll
            for (int i = 0; i < 8; ++i) {
                int node = Tn * 64 + srow[i];
                if (node > n_nodes - 1) node = n_nodes - 1;
                pf[i] = *(const float4*)(X + (size_t)node * EMBED + scol[i]);
            }
        }

        floatx4 acc[4][4];  // [mf: node tile][jf: col tile]
#pragma unroll
        for (int a = 0; a < 4; ++a)
#pragma unroll
            for (int b = 0; b < 4; ++b)
                acc[a][b] = (floatx4){0.f, 0.f, 0.f, 0.f};

#pragma unroll
        for (int ks = 0; ks < 4; ++ks) {
            const int k0 = ks * 32 + quad * 8;
            half8 xf[4];  // B-operand: B[k][n=lane&15] = Xf16[node mf*16+lm][k]
#pragma unroll
            for (int mf = 0; mf < 4; ++mf)
                xf[mf] = *(const half8*)(xs + (mf * 16 + lm) * 136 + k0);
#pragma unroll
            for (int jf = 0; jf < 4; ++jf) {
                const int j = w * 64 + jf * 16 + lm;  // A-op: WT row = out col
                const half8 wf = *(const half8*)(WT + (size_t)j * EMBED + k0);
#pragma unroll
                for (int mf = 0; mf < 4; ++mf)
                    acc[mf][jf] = __builtin_amdgcn_mfma_f32_16x16x32_f16(wf, xf[mf], acc[mf][jf], 0, 0, 0);
            }
        }
        __syncthreads();  // S2: xs reads done before outs overwrites union

        // Pack D into LDS out tile: node-major [local node][j], stride 264.
        // D: col(lane&15) = node within mf-tile, row(quad*4+r) = output col j.
#pragma unroll
        for (int mf = 0; mf < 4; ++mf) {
#pragma unroll
            for (int jf = 0; jf < 4; ++jf) {
                half4 h;
#pragma unroll
                for (int r = 0; r < 4; ++r) h[r] = (_Float16)acc[mf][jf][r];
                *(half4*)(outs + (mf * 16 + lm) * 264 + w * 64 + jf * 16 + quad * 4) = h;
            }
        }
        __syncthreads();  // S3: outs visible

        // Coalesced store: 64 nodes x 512 B contiguous in AB (node-major).
#pragma unroll
        for (int i = 0; i < 8; ++i) {
            const int idx8 = i * 256 + t;         // half8 index in 64x256 tile
            const int node = idx8 >> 5, jj = idx8 & 31;
            if (mblk + node < n_nodes)
                *(half8*)(AB + (size_t)(mblk + node) * 256 + jj * 8) =
                    *(const half8*)(outs + node * 264 + jj * 8);
        }
        __syncthreads();  // S4: outs reads done before next tile's stage
    }
}

// Hand-counted waits: sched_barrier(0) after each (rule #18 — register-only
// consumers can be hoisted past an asm waitcnt despite "memory").
#define WAITVM(N)                                              \
    do {                                                       \
        asm volatile("s_waitcnt vmcnt(" #N ")" ::: "memory");  \
        __builtin_amdgcn_sched_barrier(0);                     \
    } while (0)

// --- Kernel 2: per-edge MLP. 16 edges/group, persistent waves, 2-deep
// ping-pong pipeline where EVERY loop memory op is inline asm (gathers:
// global_load_dwordx4 "=v"; idx: global_load_dword; outputs:
// global_store_dword) with hand-counted vmcnt. The compiler cannot sink,
// re-order, or drain these; both gather sets are forced live.
__global__ __launch_bounds__(256, 3) void edge_mlp(
    const _Float16* __restrict__ AB, const int* __restrict__ eidx,
    const int* __restrict__ flag, const _Float16* __restrict__ b1f,
    const _Float16* __restrict__ W2PT, const float* __restrict__ b2,
    float* __restrict__ out, float* __restrict__ dump, int n_edges) {
    const int lane = threadIdx.x & 63, lm = lane & 15, quad = lane >> 4;
    const int W = gridDim.x * 4;               // total waves
    const int G = (n_edges + 15) / 16;         // 16-edge groups
    const int wid = blockIdx.x * 4 + (threadIdx.x >> 6);
    if (wid >= G) return;

    const int mode = *flag;        // wave-uniform: 1 => int64-layout indices
    const float b2v = b2[lm & 1];  // only meaningful when lm<2
    // Single per-wave dump dword: dead-lane stores coalesce to one line.
    const uint64_t dadr = (uint64_t)(dump + wid);
    const uint64_t qbyte = (uint64_t)(quad * 16);  // byte offset within row

    // Loop-invariant operands in registers.
    half8 wv[4], bv[4];
#pragma unroll
    for (int ks = 0; ks < 4; ++ks) {
        wv[ks] = *(const half8*)(W2PT + lm * 128 + ks * 32 + quad * 8);
        bv[ks] = *(const half8*)(b1f + ks * 32 + quad * 8);
    }
    // Consume them NOW so the compiler's own waitcnts land in the prologue,
    // not inside the loop (where they'd drain the asm pipeline).
#pragma unroll
    for (int ks = 0; ks < 4; ++ks)
        asm volatile("" :: "v"(wv[ks]), "v"(bv[ks]));
    asm volatile("" :: "v"(b2v));

    // Clamped index address for lane lm of group g (which: 0=row, 1=col).
    auto idx_addr = [&](int g, int which) -> uint64_t {
        int e = g * 16 + lm;
        e = e < n_edges ? e : n_edges - 1;
        const size_t off = which ? ((size_t)n_edges + e) : (size_t)e;
        return (uint64_t)(eidx + (off << mode));
    };

    // Issue the 8 gathers for one group (asm; no waits here).
    auto gissue = [&](int r, int c, half8* d) {
        const uint64_t ap = (uint64_t)(AB + ((size_t)(unsigned)r << 8)) + qbyte;
        const uint64_t bp = (uint64_t)(AB + ((size_t)(unsigned)c << 8) + 128) + qbyte;
        asm volatile("global_load_dwordx4 %0, %1, off"            : "=v"(d[0]) : "v"(ap));
        asm volatile("global_load_dwordx4 %0, %1, off offset:64"  : "=v"(d[1]) : "v"(ap));
        asm volatile("global_load_dwordx4 %0, %1, off offset:128" : "=v"(d[2]) : "v"(ap));
        asm volatile("global_load_dwordx4 %0, %1, off offset:192" : "=v"(d[3]) : "v"(ap));
        asm volatile("global_load_dwordx4 %0, %1, off"            : "=v"(d[4]) : "v"(bp));
        asm volatile("global_load_dwordx4 %0, %1, off offset:64"  : "=v"(d[5]) : "v"(bp));
        asm volatile("global_load_dwordx4 %0, %1, off offset:128" : "=v"(d[6]) : "v"(bp));
        asm volatile("global_load_dwordx4 %0, %1, off offset:192" : "=v"(d[7]) : "v"(bp));
    };

    // MFMA + 4 asm stores (branchless: dead lanes hit the wave dump dword).
    auto comp = [&](int g, const half8* d) {
        floatx4 acc = (floatx4){0.f, 0.f, 0.f, 0.f};
#pragma unroll
        for (int ks = 0; ks < 4; ++ks) {
            half8 h = d[ks] + d[ks + 4] + bv[ks];
#pragma unroll
            for (int j = 0; j < 8; ++j)
                h[j] = h[j] > (_Float16)0.f ? h[j] : (_Float16)0.f;
            acc = __builtin_amdgcn_mfma_f32_16x16x32_f16(h, wv[ks], acc, 0, 0, 0);
        }
        const int eb = g * 16;
#pragma unroll
        for (int r = 0; r < 4; ++r) {
            const int ed = eb + quad * 4 + r;
            const bool real = (lm < 2) & (ed < n_edges);
            const uint64_t sa = real ? (uint64_t)(out + (size_t)ed * 2 + lm) : dadr;
            const float v = acc[r] + b2v;
            asm volatile("global_store_dword %0, %1, off" :: "v"(sa), "v"(v));
        }
    };

    // ---- prologue: enter the loop in steady-state queue shape ----
    // Queue after prologue (issue order): I1(2), G0(8), Sd(4) = 14.
    int g0 = wid, g1 = wid + W;
    int r0i, c0i, r1i, c1i;
    {
        uint64_t a;
        a = idx_addr(g0, 0); asm volatile("global_load_dword %0, %1, off" : "=v"(r0i) : "v"(a));
        a = idx_addr(g0, 1); asm volatile("global_load_dword %0, %1, off" : "=v"(c0i) : "v"(a));
        a = idx_addr(g1, 0); asm volatile("global_load_dword %0, %1, off" : "=v"(r1i) : "v"(a));
        a = idx_addr(g1, 1); asm volatile("global_load_dword %0, %1, off" : "=v"(c1i) : "v"(a));
    }
    WAITVM(2);                         // I0 done (I1 may remain)
    half8 a0[8], a1[8];
    gissue(r0i, c0i, a0);              // G0: 8 outstanding
    {                                  // 4 dummy stores: match steady S(4)
        const float z = 0.f;
        asm volatile("global_store_dword %0, %1, off" :: "v"(dadr), "v"(z));
        asm volatile("global_store_dword %0, %1, off" :: "v"(dadr), "v"(z));
        asm volatile("global_store_dword %0, %1, off" :: "v"(dadr), "v"(z));
        asm volatile("global_store_dword %0, %1, off" :: "v"(dadr), "v"(z));
    }

    // ---- steady state: 2 phases/iter; waits are vmcnt(12)/vmcnt(14) ----
    const int n = (G - wid + W - 1) / W;   // real groups for this wave (>=1)
    const int nloop = (n + 1) >> 1;        // odd n => one harmless dummy phase
    for (int it = 0; it < nloop; ++it) {
        // Phase A: comp(g0,a0); gather(g1)->a1; idx(g0+2W)->r0i,c0i.
        {
            const int g2 = g1 + W;
            WAITVM(12);                          // idx(g1) ready
            uint64_t a;
            a = idx_addr(g2, 0); asm volatile("global_load_dword %0, %1, off" : "=v"(r0i) : "v"(a));
            a = idx_addr(g2, 1); asm volatile("global_load_dword %0, %1, off" : "=v"(c0i) : "v"(a));
            gissue(r1i, c1i, a1);
            WAITVM(14);                          // a0 ready
            comp(g0, a0);
        }
        // Phase B: comp(g1,a1); gather(g2)->a0; idx(g1+2W)->r1i,c1i.
        {
            const int g2 = g1 + W, g3 = g2 + W;
            WAITVM(12);                          // idx(g2) ready
            uint64_t a;
            a = idx_addr(g3, 0); asm volatile("global_load_dword %0, %1, off" : "=v"(r1i) : "v"(a));
            a = idx_addr(g3, 1); asm volatile("global_load_dword %0, %1, off" : "=v"(c1i) : "v"(a));
            gissue(r0i, c0i, a0);
            WAITVM(14);                          // a1 ready
            comp(g1, a1);
        }
        g0 += 2 * W;
        g1 += 2 * W;
    }
}

extern "C" void kernel_launch(void* const* d_in, const int* in_sizes, int n_in,
                              void* d_out, int out_size, void* d_ws, size_t ws_size,
                              hipStream_t stream) {
    const float* X   = (const float*)d_in[0];
    const int*   idx = (const int*)d_in[1];
    const float* W1  = (const float*)d_in[2];
    const float* b1  = (const float*)d_in[3];
    const float* W2  = (const float*)d_in[4];
    const float* b2  = (const float*)d_in[5];
    float* out = (float*)d_out;

    const int n_nodes = in_sizes[0] / EMBED;   // 100000
    const int n_edges = in_sizes[1] / 2;       // 500000

    // ws: flag @0 | AB @256 (n_nodes*512 B) | WT 64KB | W2PT 4KB | b1f 256B
    //     | dump 3072 floats
    char* ws = (char*)d_ws;
    int*      flag = (int*)ws;
    _Float16* AB   = (_Float16*)(ws + 256);
    _Float16* WT   = (_Float16*)(ws + 256 + (size_t)n_nodes * 512);
    _Float16* W2PT = WT + 256 * 128;
    _Float16* b1f  = W2PT + 16 * 128;
    float*    dump = (float*)(b1f + 128);

    const int n_tiles = (n_nodes + 63) / 64;   // 1563

    prep<<<129, 256, 0, stream>>>(W1, W2, b1, idx, WT, W2PT, b1f, flag);
    gemm_ab<<<782, 256, 0, stream>>>(X, WT, AB, n_nodes, n_tiles);
    // 768 persistent blocks = 3 blocks/CU x 4 waves = 12 waves/CU at the
    // (256,3) VGPR cap; ~10 groups/wave keeps the 2-deep pipeline filled.
    edge_mlp<<<768, 256, 0, stream>>>(
        AB, idx, flag, b1f, W2PT, b2, out, dump, n_edges);
}